// Round 9
// baseline (11.891 us; speedup 1.0000x reference)
//
#include <hip/hip_runtime.h>
#include <float.h>

// Problem constants (from reference)
#define NB 5                    // N_BANDS
#define BB 256                  // B
#define LL 800                  // L
#define TT (NB * LL)            // 4000 values per batch row
#define NN (TT - NB)            // 3995 output diffs per row

constexpr int BLOCK = 1024;     // 16 waves, one block per row
constexpr int NBUK  = 4096;     // lambda ~= 0.98
constexpr int NV4   = TT / 4;   // 1000 float4 loads cover the row exactly

__global__ __launch_bounds__(BLOCK)
void bucket_rank_diff4(const float* __restrict__ in,
                       const int* __restrict__ ntotal,
                       float* __restrict__ out)
{
    __shared__ __align__(16) float scat[TT];        // bucket-grouped values
    __shared__ __align__(16) float srt[TT + 8];     // sorted; +8 pad for b128 tail
    __shared__ __align__(16) int   cnt[NBUK];       // histogram (atomic returns offset); never overwritten
    __shared__ __align__(16) int   bstart[NBUK];    // bucket begin
    __shared__ int wsum[16];                        // per-wave scan totals

    const int b    = blockIdx.x;
    const int tid  = threadIdx.x;
    const int lane = tid & 63;
    const int wid  = tid >> 6;
    const bool active = (tid < NV4);
    const float scale = (float)NBUK / 1000.0f;      // monotone map, vals in [0,1000)

    // ---- Prefetch: issue global loads BEFORE init+barrier (latency hides).
    float4 x4 = make_float4(0.f, 0.f, 0.f, 0.f);
    if (active) {
        int band = tid / 200;            // 200 float4 per (band,row) chunk of 800
        int l4   = tid - band * 200;
        x4 = *(reinterpret_cast<const float4*>(in + (band * BB + b) * LL) + l4);
    }
    const int nt = ntotal[b];

    // init histogram: 4096 ints / 1024 threads = one int4 each
    *reinterpret_cast<int4*>(&cnt[tid * 4]) = make_int4(0, 0, 0, 0);
    __syncthreads();                                            // (1)

    // ---- Phase 1: classify; histogram atomic returns in-bucket arrival offset.
    float v[4];
    int   g[4];
    int   off[4];
    if (active) {
        v[0] = x4.x; v[1] = x4.y; v[2] = x4.z; v[3] = x4.w;
        #pragma unroll
        for (int k = 0; k < 4; ++k) {
            int gg = (int)(v[k] * scale);
            gg = gg < 0 ? 0 : (gg > NBUK - 1 ? NBUK - 1 : gg);
            g[k]   = gg;
            off[k] = atomicAdd(&cnt[gg], 1);
        }
    } else {
        g[0] = g[1] = g[2] = g[3] = -1;
    }
    __syncthreads();                                            // (2)

    // ---- Phase 2a: per-element bucket counts (independent of the scan below;
    //      cnt[] is final and never overwritten).
    int bc[4];
    #pragma unroll
    for (int k = 0; k < 4; ++k) bc[k] = (g[k] >= 0) ? cnt[g[k]] : 0;

    // ---- Phase 2b: exclusive prefix sum over 4096 bucket counts.
    int4 cq = *reinterpret_cast<int4*>(&cnt[tid * 4]);
    int  c0 = cq.x, c1 = cq.y, c2 = cq.z, c3 = cq.w;
    int  s  = c0 + c1 + c2 + c3;
    int  inc = s;
    #pragma unroll
    for (int d = 1; d < 64; d <<= 1) {
        int t = __shfl_up(inc, d);
        if (lane >= d) inc += t;
    }
    if (lane == 63) wsum[wid] = inc;
    __syncthreads();                                            // (3)
    int wo = 0;
    #pragma unroll
    for (int w = 0; w < 16; ++w) wo += (w < wid) ? wsum[w] : 0;
    int run = (inc - s) + wo;
    *reinterpret_cast<int4*>(&bstart[tid * 4]) =
        make_int4(run, run + c0, run + c0 + c1, run + c0 + c1 + c2);
    __syncthreads();                                            // (4)

    // ---- Phase 3: deterministic scatter; keep bucket base in registers.
    int pbase[4];
    if (active) {
        #pragma unroll
        for (int k = 0; k < 4; ++k) {
            pbase[k] = bstart[g[k]];
            scat[pbase[k] + off[k]] = v[k];
        }
    }
    __syncthreads();                                            // (5)

    // ---- Phase 4: rank-count within bucket — no bstart reads, singleton skip.
    if (active) {
        #pragma unroll
        for (int k = 0; k < 4; ++k) {
            int lo = pbase[k];
            if (bc[k] == 1) {
                srt[lo] = v[k];                 // ~37% of elements: rank known
            } else {
                float x = v[k];
                int   p = lo + off[k];          // my scat index (unique tie-break)
                int   r = lo;
                int   hi = lo + bc[k];
                for (int j = lo; j < hi; ++j) {
                    float w = scat[j];
                    if (w < x || (w == x && j < p)) ++r;
                }
                srt[r] = x;
            }
        }
    }
    __syncthreads();                                            // (6)

    // ---- Phase 5: adjacent diffs via two aligned b128 LDS reads per thread.
    // out[i] = srt[i+5] - srt[i+4]; let j0 = 4 + 4*tid (16B-aligned).
    if (tid < 999) {
        int j0 = 4 + 4 * tid;
        float4 q0 = *reinterpret_cast<const float4*>(&srt[j0]);
        float4 q1 = *reinterpret_cast<const float4*>(&srt[j0 + 4]);  // tail pad ok
        float d0 = q0.y - q0.x;
        float d1 = q0.z - q0.y;
        float d2 = q0.w - q0.z;
        float d3 = q1.x - q0.w;
        int i0 = 4 * tid;
        float* o = out + b * NN + i0;
        // nt <= NN-?; indices i0..i0+2 <= 3994 always valid; i0+3 == 3995 only at
        // tid==998, and nt <= 3995 makes (i < nt) false there — but we must still
        // guard the WRITE for i==3995 (out of row).
        o[0] = (i0     < nt) ? d0 : 0.0f;
        o[1] = (i0 + 1 < nt) ? d1 : 0.0f;
        o[2] = (i0 + 2 < nt) ? d2 : 0.0f;
        if (i0 + 3 < NN) o[3] = (i0 + 3 < nt) ? d3 : 0.0f;
    }
}

extern "C" void kernel_launch(void* const* d_in, const int* in_sizes, int n_in,
                              void* d_out, int out_size, void* d_ws, size_t ws_size,
                              hipStream_t stream) {
    const float* in  = (const float*)d_in[0];   // (5, 256, 800) fp32
    const int*   nt  = (const int*)d_in[1];     // (256,) int32
    float*       out = (float*)d_out;           // (256, 3995) fp32
    (void)in_sizes; (void)n_in; (void)out_size; (void)d_ws; (void)ws_size;
    bucket_rank_diff4<<<BB, BLOCK, 0, stream>>>(in, nt, out);
}

// Round 10
// 11.517 us; speedup vs baseline: 1.0325x; 1.0325x over previous
//
#include <hip/hip_runtime.h>
#include <float.h>

// Problem constants (from reference)
#define NB 5                    // N_BANDS
#define BB 256                  // B
#define LL 800                  // L
#define TT (NB * LL)            // 4000 values per batch row
#define NN (TT - NB)            // 3995 output diffs per row

constexpr int BLOCK = 1024;     // 16 waves, one block per row
constexpr int NBUK  = 8192;     // lambda ~= 0.49 -> window-rank almost always fits
constexpr int NV4   = TT / 4;   // 1000 float4 loads cover the row exactly

__global__ __launch_bounds__(BLOCK)
void bucket_wrank_diff(const float* __restrict__ in,
                       const int* __restrict__ ntotal,
                       float* __restrict__ out)
{
    __shared__ __align__(16) float scat[TT + 8];    // bucket-grouped; +8 FLT_MAX pad
    __shared__ __align__(16) float srt[TT + 8];     // sorted; +8 pad for b128 diff tail
    __shared__ __align__(16) int   cnt[NBUK];       // histogram (atomic returns offset)
    __shared__ __align__(16) int   bstart[NBUK];    // bucket begin
    __shared__ int wsum[16];                        // per-wave scan totals

    const int b    = blockIdx.x;
    const int tid  = threadIdx.x;
    const int lane = tid & 63;
    const int wid  = tid >> 6;
    const bool active = (tid < NV4);
    const float scale = (float)NBUK / 1000.0f;      // monotone map, vals in [0,1000)

    // ---- Prefetch global loads BEFORE init+barrier (hide HBM latency).
    float4 x4 = make_float4(0.f, 0.f, 0.f, 0.f);
    if (active) {
        int band = tid / 200;            // 200 float4 per (band,row) chunk of 800
        int l4   = tid - band * 200;
        x4 = *(reinterpret_cast<const float4*>(in + (band * BB + b) * LL) + l4);
    }
    const int nt = ntotal[b];

    // init histogram: 8192 ints / 1024 threads = 2 x int4 each; pad scat.
    *reinterpret_cast<int4*>(&cnt[tid * 8])     = make_int4(0, 0, 0, 0);
    *reinterpret_cast<int4*>(&cnt[tid * 8 + 4]) = make_int4(0, 0, 0, 0);
    if (tid < 8) scat[TT + tid] = FLT_MAX;          // window overrun guard
    __syncthreads();                                            // (1)

    // ---- Phase 1: classify; histogram atomic returns in-bucket arrival offset.
    float v[4];
    int   g[4];
    int   off[4];
    if (active) {
        v[0] = x4.x; v[1] = x4.y; v[2] = x4.z; v[3] = x4.w;
        #pragma unroll
        for (int k = 0; k < 4; ++k) {
            int gg = (int)(v[k] * scale);
            gg = gg < 0 ? 0 : (gg > NBUK - 1 ? NBUK - 1 : gg);
            g[k]   = gg;
            off[k] = atomicAdd(&cnt[gg], 1);
        }
    } else {
        g[0] = g[1] = g[2] = g[3] = -1;
    }
    __syncthreads();                                            // (2)

    // ---- Phase 2a: per-element bucket sizes (cnt[] is final, never overwritten).
    int bc[4];
    #pragma unroll
    for (int k = 0; k < 4; ++k) bc[k] = (g[k] >= 0) ? cnt[g[k]] : 0;

    // ---- Phase 2b: exclusive prefix sum over 8192 bucket counts (8/thread).
    int4 q0 = *reinterpret_cast<int4*>(&cnt[tid * 8]);
    int4 q1 = *reinterpret_cast<int4*>(&cnt[tid * 8 + 4]);
    int c[8] = {q0.x, q0.y, q0.z, q0.w, q1.x, q1.y, q1.z, q1.w};
    int s = 0;
    #pragma unroll
    for (int k = 0; k < 8; ++k) s += c[k];
    int inc = s;
    #pragma unroll
    for (int d = 1; d < 64; d <<= 1) {
        int t = __shfl_up(inc, d);
        if (lane >= d) inc += t;
    }
    if (lane == 63) wsum[wid] = inc;
    __syncthreads();                                            // (3)
    int wo = 0;
    #pragma unroll
    for (int w = 0; w < 16; ++w) wo += (w < wid) ? wsum[w] : 0;
    int run = (inc - s) + wo;
    int bs[8];
    #pragma unroll
    for (int k = 0; k < 8; ++k) { bs[k] = run; run += c[k]; }
    *reinterpret_cast<int4*>(&bstart[tid * 8])     = make_int4(bs[0], bs[1], bs[2], bs[3]);
    *reinterpret_cast<int4*>(&bstart[tid * 8 + 4]) = make_int4(bs[4], bs[5], bs[6], bs[7]);
    __syncthreads();                                            // (4)

    // ---- Phase 3: deterministic scatter; keep bucket base in registers.
    int pbase[4];
    if (active) {
        #pragma unroll
        for (int k = 0; k < 4; ++k) {
            pbase[k] = bstart[g[k]];
            scat[pbase[k] + off[k]] = v[k];
        }
    }
    __syncthreads();                                            // (5)

    // ---- Phase 4: window rank — 2 independent b128 reads + 8 flat compares.
    // Buckets pack ascending, map is monotone: slots j<lo are strictly smaller
    // (count +1 each), slots j>=hi strictly larger (+0), so counting over the
    // FULL window with base r=wb is exact — no in-window masking needed.
    if (active) {
        #pragma unroll
        for (int k = 0; k < 4; ++k) {
            int   lo = pbase[k];
            float x  = v[k];
            int   p  = lo + off[k];          // my scat index (unique tie-break)
            int   wb = lo & ~3;
            if ((lo & 3) + bc[k] <= 8) {     // bucket fits the 8-slot window
                float4 a = *reinterpret_cast<const float4*>(&scat[wb]);
                float4 d = *reinterpret_cast<const float4*>(&scat[wb + 4]);
                float ws8[8] = {a.x, a.y, a.z, a.w, d.x, d.y, d.z, d.w};
                int r = wb;
                #pragma unroll
                for (int t = 0; t < 8; ++t) {
                    int j = wb + t;
                    r += (ws8[t] < x || (ws8[t] == x && j < p)) ? 1 : 0;
                }
                srt[r] = x;
            } else {                          // rare oversize bucket: scalar loop
                int r = lo, hi = lo + bc[k];
                for (int j = lo; j < hi; ++j) {
                    float w = scat[j];
                    if (w < x || (w == x && j < p)) ++r;
                }
                srt[r] = x;
            }
        }
    }
    __syncthreads();                                            // (6)

    // ---- Phase 5: adjacent diffs via two aligned b128 LDS reads per thread.
    if (tid < 999) {
        int j0 = 4 + 4 * tid;                 // 16B-aligned
        float4 p0 = *reinterpret_cast<const float4*>(&srt[j0]);
        float4 p1 = *reinterpret_cast<const float4*>(&srt[j0 + 4]);   // pad-safe
        float d0 = p0.y - p0.x;
        float d1 = p0.z - p0.y;
        float d2 = p0.w - p0.z;
        float d3 = p1.x - p0.w;
        int i0 = 4 * tid;
        float* o = out + b * NN + i0;
        o[0] = (i0     < nt) ? d0 : 0.0f;
        o[1] = (i0 + 1 < nt) ? d1 : 0.0f;
        o[2] = (i0 + 2 < nt) ? d2 : 0.0f;
        if (i0 + 3 < NN) o[3] = (i0 + 3 < nt) ? d3 : 0.0f;
    }
}

extern "C" void kernel_launch(void* const* d_in, const int* in_sizes, int n_in,
                              void* d_out, int out_size, void* d_ws, size_t ws_size,
                              hipStream_t stream) {
    const float* in  = (const float*)d_in[0];   // (5, 256, 800) fp32
    const int*   nt  = (const int*)d_in[1];     // (256,) int32
    float*       out = (float*)d_out;           // (256, 3995) fp32
    (void)in_sizes; (void)n_in; (void)out_size; (void)d_ws; (void)ws_size;
    bucket_wrank_diff<<<BB, BLOCK, 0, stream>>>(in, nt, out);
}